// Round 1
// baseline (1146.456 us; speedup 1.0000x reference)
//
#include <hip/hip_runtime.h>

namespace {

constexpr int L = 2048, Bb = 2, E = 1024, H = 16, D = 64;
constexpr int M = L * Bb;              // 4096 rows (l*B + b)
constexpr int CHK = 128, NC = L / CHK; // 16 chunks
constexpr int BH = Bb * H;             // 32
constexpr int STS = D * D + D;         // 4160 floats per chunk-state
constexpr float EPS = 1e-4f;

// ---------------- f32 tiled GEMM:  C = A(MxK) * W(NxK)^T + bias ----------------
// MODE 0: C row-major MxN -> d_out[(l*B+b)*E + c]
// MODE 1: scatter to (b,h,n,d) layout: out[((b*H+h)*L + n)*D + d]
constexpr int BM = 128, BN = 128, BK = 8;

template <int MODE>
__launch_bounds__(256)
__global__ void gemm_nt(const float* __restrict__ A, const float* __restrict__ W,
                        const float* __restrict__ bias, float* __restrict__ Cdst) {
  __shared__ float As[BK][BM + 1];
  __shared__ float Bs[BK][BN + 1];
  const int tid = threadIdx.x;
  const int tx = tid & 15, ty = tid >> 4;
  const int row0 = blockIdx.y * BM, col0 = blockIdx.x * BN;
  const int lrow = tid >> 1;          // 0..127
  const int lpart = (tid & 1) * 4;    // 0 or 4
  float acc[8][8] = {};
  const float* Aptr = A + (size_t)(row0 + lrow) * E + lpart;
  const float* Wptr = W + (size_t)(col0 + lrow) * E + lpart;
  for (int kt = 0; kt < E; kt += BK) {
    const float4 a4 = *reinterpret_cast<const float4*>(Aptr + kt);
    const float4 b4 = *reinterpret_cast<const float4*>(Wptr + kt);
    __syncthreads();
    As[lpart + 0][lrow] = a4.x; As[lpart + 1][lrow] = a4.y;
    As[lpart + 2][lrow] = a4.z; As[lpart + 3][lrow] = a4.w;
    Bs[lpart + 0][lrow] = b4.x; Bs[lpart + 1][lrow] = b4.y;
    Bs[lpart + 2][lrow] = b4.z; Bs[lpart + 3][lrow] = b4.w;
    __syncthreads();
#pragma unroll
    for (int kk = 0; kk < BK; ++kk) {
      float ar[8], br[8];
#pragma unroll
      for (int i = 0; i < 8; ++i) ar[i] = As[kk][ty * 8 + i];
#pragma unroll
      for (int j = 0; j < 8; ++j) br[j] = Bs[kk][tx * 8 + j];
#pragma unroll
      for (int i = 0; i < 8; ++i)
#pragma unroll
        for (int j = 0; j < 8; ++j) acc[i][j] += ar[i] * br[j];
    }
  }
#pragma unroll
  for (int i = 0; i < 8; ++i) {
    const int r = row0 + ty * 8 + i;
#pragma unroll
    for (int j = 0; j < 8; ++j) {
      const int c = col0 + tx * 8 + j;
      const float v = acc[i][j] + bias[c];
      if (MODE == 0) {
        Cdst[(size_t)r * E + c] = v;
      } else {
        const int n = r >> 1, b = r & 1;   // B = 2
        const int h = c >> 6, dd = c & 63; // D = 64
        Cdst[(((size_t)(b * H + h)) * L + n) * D + dd] = v;
      }
    }
  }
}

// ---------------- relu + interleaved RoPE (in place, (bh,n,d) layout) ----------------
__launch_bounds__(256)
__global__ void relu_rope(float* __restrict__ q, float* __restrict__ k) {
  const size_t total = (size_t)BH * L * (D / 2); // 2,097,152 pairs per tensor
  size_t idx = (size_t)blockIdx.x * 256 + threadIdx.x;
  float* p = q;
  if (idx >= total) { p = k; idx -= total; }
  const int i = (int)(idx & 31);            // pair index 0..31
  const int n = (int)((idx >> 5) & (L - 1));
  const size_t bh = idx >> 16;              // L*32 = 65536
  const size_t base = (bh * L + n) * D + 2 * i;
  // theta_i = 10000^(-i/32) = exp(-i * ln(10000)/32)
  const float theta = expf(-(float)i * 0.2878231366242557f);
  float s, c;
  sincosf((float)n * theta, &s, &c);
  const float x0 = fmaxf(p[base], 0.f);
  const float x1 = fmaxf(p[base + 1], 0.f);
  p[base] = x0 * c - x1 * s;
  p[base + 1] = x0 * s + x1 * c;
}

// ---------------- pass 1: per-chunk states S_c = K_c^T V_c, ksum_c ----------------
__launch_bounds__(256)
__global__ void attn_state(const float* __restrict__ Kt, const float* __restrict__ Vt,
                           float* __restrict__ st) {
  __shared__ float Ks[CHK][D + 1];
  __shared__ float Vs[CHK][D + 1];
  const int bx = blockIdx.x;
  const int bh = bx / NC, c = bx % NC;
  const int tid = threadIdx.x;
  const size_t gbase = ((size_t)bh * L + (size_t)c * CHK) * D;
  for (int idx = tid; idx < CHK * D; idx += 256) {
    const int m = idx >> 6, d = idx & 63;
    Ks[m][d] = Kt[gbase + idx];
    Vs[m][d] = Vt[gbase + idx];
  }
  __syncthreads();
  const int d0 = (tid & 15) * 4, e0 = (tid >> 4) * 4;
  float acc[4][4] = {};
  for (int m = 0; m < CHK; ++m) {
    float a[4], b[4];
#pragma unroll
    for (int i = 0; i < 4; ++i) a[i] = Ks[m][d0 + i];
#pragma unroll
    for (int j = 0; j < 4; ++j) b[j] = Vs[m][e0 + j];
#pragma unroll
    for (int i = 0; i < 4; ++i)
#pragma unroll
      for (int j = 0; j < 4; ++j) acc[i][j] += a[i] * b[j];
  }
  float* stp = st + (size_t)bx * STS;
#pragma unroll
  for (int i = 0; i < 4; ++i)
#pragma unroll
    for (int j = 0; j < 4; ++j) stp[(d0 + i) * D + e0 + j] = acc[i][j];
  if (tid < D) {
    float s = 0.f;
    for (int m = 0; m < CHK; ++m) s += Ks[m][tid];
    stp[D * D + tid] = s;
  }
}

// ---------------- pass 2: in-place exclusive prefix scan over chunks ----------------
__launch_bounds__(256)
__global__ void attn_scan(float* __restrict__ st) {
  const int bh = blockIdx.x;
  for (int j = threadIdx.x; j < STS; j += 256) {
    float run = 0.f;
    for (int c = 0; c < NC; ++c) {
      const size_t o = ((size_t)(bh * NC + c)) * STS + j;
      const float v = st[o];
      st[o] = run;
      run += v;
    }
  }
}

// ---------------- pass 3: per-chunk output (inter via state + intra causal) ----------------
__launch_bounds__(256)
__global__ void attn_out(const float* __restrict__ Qt, const float* __restrict__ Kt,
                         const float* __restrict__ Vt, const float* __restrict__ st,
                         float* __restrict__ Ot) {
  __shared__ float Qs[CHK][D + 1];
  __shared__ float Ks2[CHK][D + 1];
  __shared__ float Vs2[CHK][D + 1];
  __shared__ float Ss[D][D + 1];
  __shared__ float ksx[D];
  const int bx = blockIdx.x;
  const int bh = bx / NC, c = bx % NC;
  const int tid = threadIdx.x;
  const size_t gbase = ((size_t)bh * L + (size_t)c * CHK) * D;
  for (int idx = tid; idx < CHK * D; idx += 256) {
    const int m = idx >> 6, d = idx & 63;
    Qs[m][d] = Qt[gbase + idx];
    Ks2[m][d] = Kt[gbase + idx];
    Vs2[m][d] = Vt[gbase + idx];
  }
  const float* stp = st + (size_t)bx * STS;
  for (int idx = tid; idx < D * D; idx += 256) Ss[idx >> 6][idx & 63] = stp[idx];
  if (tid < D) ksx[tid] = stp[D * D + tid];
  __syncthreads();
  const int n = tid >> 1, e0 = (tid & 1) * 32;
  float o[32];
#pragma unroll
  for (int e = 0; e < 32; ++e) o[e] = 0.f;
  float rowsum = 0.f;
  // inter-chunk: q_n . S_excl  and  q_n . ksum_excl
  for (int d = 0; d < D; ++d) {
    const float qd = Qs[n][d];
    rowsum += qd * ksx[d];
#pragma unroll
    for (int e = 0; e < 32; ++e) o[e] += qd * Ss[d][e0 + e];
  }
  // intra-chunk causal
  for (int m = 0; m <= n; ++m) {
    float s = 0.f;
#pragma unroll
    for (int d = 0; d < D; ++d) s += Qs[n][d] * Ks2[m][d];
    rowsum += s;
#pragma unroll
    for (int e = 0; e < 32; ++e) o[e] += s * Vs2[m][e0 + e];
  }
  const float inv = 1.f / fmaxf(rowsum, EPS);
  const int nglob = c * CHK + n;
  const int b = bh >> 4, h = bh & 15; // bh = b*H + h
  float* op = Ot + ((size_t)nglob * Bb + b) * E + (size_t)h * D + e0;
#pragma unroll
  for (int e = 0; e < 32; ++e) op[e] = o[e] * inv;
}

} // namespace

extern "C" void kernel_launch(void* const* d_in, const int* in_sizes, int n_in,
                              void* d_out, int out_size, void* d_ws, size_t ws_size,
                              hipStream_t stream) {
  (void)in_sizes; (void)n_in; (void)out_size; (void)ws_size;
  const float* query = (const float*)d_in[0];
  const float* key_  = (const float*)d_in[1];
  const float* value = (const float*)d_in[2];
  const float* q_w   = (const float*)d_in[3];
  const float* q_b   = (const float*)d_in[4];
  const float* k_w   = (const float*)d_in[5];
  const float* k_b   = (const float*)d_in[6];
  const float* v_w   = (const float*)d_in[7];
  const float* v_b   = (const float*)d_in[8];
  const float* out_w = (const float*)d_in[9];
  const float* out_b = (const float*)d_in[10];
  float* out = (float*)d_out;

  float* ws = (float*)d_ws;
  const size_t SZ = (size_t)M * E; // 4,194,304 floats per tensor
  float* q_ws = ws;
  float* k_ws = ws + SZ;
  float* v_ws = ws + 2 * SZ;
  float* o_ws = ws + 3 * SZ;
  float* st   = ws + 4 * SZ;       // 32*16*4160 floats ~ 8.5 MB

  const dim3 gg(E / BN, M / BM);   // (8, 32)
  hipLaunchKernelGGL((gemm_nt<1>), gg, dim3(256), 0, stream, query, q_w, q_b, q_ws);
  hipLaunchKernelGGL((gemm_nt<1>), gg, dim3(256), 0, stream, key_,  k_w, k_b, k_ws);
  hipLaunchKernelGGL((gemm_nt<1>), gg, dim3(256), 0, stream, value, v_w, v_b, v_ws);
  hipLaunchKernelGGL(relu_rope, dim3(2 * BH * L * (D / 2) / 256), dim3(256), 0, stream, q_ws, k_ws);
  hipLaunchKernelGGL(attn_state, dim3(BH * NC), dim3(256), 0, stream, k_ws, v_ws, st);
  hipLaunchKernelGGL(attn_scan, dim3(BH), dim3(256), 0, stream, st);
  hipLaunchKernelGGL(attn_out, dim3(BH * NC), dim3(256), 0, stream, q_ws, k_ws, v_ws, st, o_ws);
  hipLaunchKernelGGL((gemm_nt<0>), gg, dim3(256), 0, stream, o_ws, out_w, out_b, out);
}

// Round 2
// 418.113 us; speedup vs baseline: 2.7420x; 2.7420x over previous
//
#include <hip/hip_runtime.h>

namespace {

constexpr int L = 2048, Bb = 2, E = 1024, H = 16, D = 64;
constexpr int M = L * Bb;              // 4096 rows (l*B + b)
constexpr int CHK = 128, NC = L / CHK; // 16 chunks
constexpr int BH = Bb * H;             // 32
constexpr int STS = D * D + D;         // 4160 floats per chunk-state
constexpr float EPS = 1e-4f;

using bf16 = __bf16;
typedef __attribute__((ext_vector_type(8))) __bf16 bf16x8;
typedef __attribute__((ext_vector_type(4))) float f32x4;

#define GLDS16(ldsdst, gsrc)                                      \
  __builtin_amdgcn_global_load_lds(                               \
      (const __attribute__((address_space(1))) void*)(gsrc),      \
      (__attribute__((address_space(3))) void*)(ldsdst), 16, 0, 0)

// ---------------- f32 -> bf16 hi/lo split (8 elements / thread) ----------------
__launch_bounds__(256)
__global__ void split_conv(const float* __restrict__ x, bf16* __restrict__ hi,
                           bf16* __restrict__ lo, int n8) {
  const int idx = blockIdx.x * 256 + threadIdx.x;
  if (idx >= n8) return;
  const float4* p = reinterpret_cast<const float4*>(x) + (size_t)idx * 2;
  const float4 a = p[0], b = p[1];
  const float v[8] = {a.x, a.y, a.z, a.w, b.x, b.y, b.z, b.w};
  bf16x8 h, l;
#pragma unroll
  for (int j = 0; j < 8; ++j) {
    const bf16 hb = (bf16)v[j];
    h[j] = hb;
    l[j] = (bf16)(v[j] - (float)hb);
  }
  *reinterpret_cast<bf16x8*>(hi + (size_t)idx * 8) = h;
  *reinterpret_cast<bf16x8*>(lo + (size_t)idx * 8) = l;
}

// ------------- split-bf16 MFMA GEMM:  C = A(4096x1024) * W(1024x1024)^T + bias -------------
// A, W given as bf16 hi/lo pairs; product via 3-term MFMA (hi*hi + hi*lo + lo*hi).
// MODE 0: C row-major -> Cdst[r*E + c]
// MODE 1: scatter to (b,h,n,d): Cdst[((b*H+h)*L + n)*D + d]
constexpr int GBM = 128, GBN = 64, GBK = 32;

template <int MODE>
__launch_bounds__(256)
__global__ void gemm_split(const bf16* __restrict__ Ahi, const bf16* __restrict__ Alo,
                           const bf16* __restrict__ Whi, const bf16* __restrict__ Wlo,
                           const float* __restrict__ bias, float* __restrict__ Cdst) {
  __shared__ __align__(16) unsigned short sAhi[GBM * GBK];
  __shared__ __align__(16) unsigned short sAlo[GBM * GBK];
  __shared__ __align__(16) unsigned short sBhi[GBN * GBK];
  __shared__ __align__(16) unsigned short sBlo[GBN * GBK];
  const int tid = threadIdx.x;
  const int row0 = blockIdx.y * GBM, col0 = blockIdx.x * GBN;
  const int lane = tid & 63, wid = tid >> 6;
  const int wr = wid >> 1, wc = wid & 1;       // 2x2 waves; wave tile 64x32
  const int fr = lane & 15, kg = lane >> 4;    // fragment row/col, k-group
  f32x4 acc[4][2] = {};

  const int lin = tid * 8;                     // staging element index (issue 0)
  const int ar0 = lin >> 5, ac0 = lin & 31;    // A/B tile row, col for issue 0
  const int ar1 = (lin + 2048) >> 5;           // A issue 1 row (col same)

  const size_t K = E;
  for (int kt = 0; kt < E; kt += GBK) {
    // stage A (128x32) hi+lo: 2 issues each; B (64x32) hi+lo: 1 issue each
    GLDS16(&sAhi[lin],        Ahi + (size_t)(row0 + ar0) * K + kt + ac0);
    GLDS16(&sAhi[lin + 2048], Ahi + (size_t)(row0 + ar1) * K + kt + ac0);
    GLDS16(&sAlo[lin],        Alo + (size_t)(row0 + ar0) * K + kt + ac0);
    GLDS16(&sAlo[lin + 2048], Alo + (size_t)(row0 + ar1) * K + kt + ac0);
    GLDS16(&sBhi[lin],        Whi + (size_t)(col0 + ar0) * K + kt + ac0);
    GLDS16(&sBlo[lin],        Wlo + (size_t)(col0 + ar0) * K + kt + ac0);
    __syncthreads();  // compiler drains vmcnt before barrier

    bf16x8 ah[4], al[4], bh[2], bl[2];
#pragma unroll
    for (int m = 0; m < 4; ++m) {
      const int off = (wr * 64 + m * 16 + fr) * GBK + kg * 8;
      ah[m] = *reinterpret_cast<const bf16x8*>(&sAhi[off]);
      al[m] = *reinterpret_cast<const bf16x8*>(&sAlo[off]);
    }
#pragma unroll
    for (int n = 0; n < 2; ++n) {
      const int off = (wc * 32 + n * 16 + fr) * GBK + kg * 8;
      bh[n] = *reinterpret_cast<const bf16x8*>(&sBhi[off]);
      bl[n] = *reinterpret_cast<const bf16x8*>(&sBlo[off]);
    }
#pragma unroll
    for (int m = 0; m < 4; ++m)
#pragma unroll
      for (int n = 0; n < 2; ++n) {
        acc[m][n] = __builtin_amdgcn_mfma_f32_16x16x32_bf16(ah[m], bh[n], acc[m][n], 0, 0, 0);
        acc[m][n] = __builtin_amdgcn_mfma_f32_16x16x32_bf16(ah[m], bl[n], acc[m][n], 0, 0, 0);
        acc[m][n] = __builtin_amdgcn_mfma_f32_16x16x32_bf16(al[m], bh[n], acc[m][n], 0, 0, 0);
      }
    __syncthreads();
  }

  // epilogue: C/D frag layout col=lane&15, row=(lane>>4)*4+i  [m89 verified]
#pragma unroll
  for (int m = 0; m < 4; ++m) {
    const int rbase = row0 + wr * 64 + m * 16 + kg * 4;
#pragma unroll
    for (int n = 0; n < 2; ++n) {
      const int c = col0 + wc * 32 + n * 16 + fr;
      const float bia = bias[c];
#pragma unroll
      for (int i = 0; i < 4; ++i) {
        const float v = acc[m][n][i] + bia;
        const int r = rbase + i;
        if (MODE == 0) {
          Cdst[(size_t)r * E + c] = v;
        } else {
          const int nn = r >> 1, b = r & 1;   // B = 2
          const int h = c >> 6, dd = c & 63;  // D = 64
          Cdst[(((size_t)(b * H + h)) * L + nn) * D + dd] = v;
        }
      }
    }
  }
}

// ---------------- relu + interleaved RoPE (in place, (bh,n,d) layout) ----------------
__launch_bounds__(256)
__global__ void relu_rope(float* __restrict__ q, float* __restrict__ k) {
  const size_t total = (size_t)BH * L * (D / 2); // 2,097,152 pairs per tensor
  size_t idx = (size_t)blockIdx.x * 256 + threadIdx.x;
  float* p = q;
  if (idx >= total) { p = k; idx -= total; }
  const int i = (int)(idx & 31);            // pair index 0..31
  const int n = (int)((idx >> 5) & (L - 1));
  const size_t bh = idx >> 16;              // L*32 = 65536
  const size_t base = (bh * L + n) * D + 2 * i;
  const float theta = expf(-(float)i * 0.2878231366242557f); // 10000^(-i/32)
  float s, c;
  sincosf((float)n * theta, &s, &c);
  const float x0 = fmaxf(p[base], 0.f);
  const float x1 = fmaxf(p[base + 1], 0.f);
  p[base] = x0 * c - x1 * s;
  p[base + 1] = x0 * s + x1 * c;
}

// ---------------- pass 1: per-chunk states S_c = K_c^T V_c, ksum_c ----------------
__launch_bounds__(256)
__global__ void attn_state(const float* __restrict__ Kt, const float* __restrict__ Vt,
                           float* __restrict__ st) {
  __shared__ float Ks[CHK][D + 1];
  __shared__ float Vs[CHK][D + 1];
  const int bx = blockIdx.x;
  const int bh = bx / NC, c = bx % NC;
  const int tid = threadIdx.x;
  const size_t gbase = ((size_t)bh * L + (size_t)c * CHK) * D;
  for (int idx = tid; idx < CHK * D; idx += 256) {
    const int m = idx >> 6, d = idx & 63;
    Ks[m][d] = Kt[gbase + idx];
    Vs[m][d] = Vt[gbase + idx];
  }
  __syncthreads();
  const int d0 = (tid & 15) * 4, e0 = (tid >> 4) * 4;
  float acc[4][4] = {};
  for (int m = 0; m < CHK; ++m) {
    float a[4], b[4];
#pragma unroll
    for (int i = 0; i < 4; ++i) a[i] = Ks[m][d0 + i];
#pragma unroll
    for (int j = 0; j < 4; ++j) b[j] = Vs[m][e0 + j];
#pragma unroll
    for (int i = 0; i < 4; ++i)
#pragma unroll
      for (int j = 0; j < 4; ++j) acc[i][j] += a[i] * b[j];
  }
  float* stp = st + (size_t)bx * STS;
#pragma unroll
  for (int i = 0; i < 4; ++i)
#pragma unroll
    for (int j = 0; j < 4; ++j) stp[(d0 + i) * D + e0 + j] = acc[i][j];
  if (tid < D) {
    float s = 0.f;
    for (int m = 0; m < CHK; ++m) s += Ks[m][tid];
    stp[D * D + tid] = s;
  }
}

// ---------------- pass 2: in-place exclusive prefix scan over chunks ----------------
__launch_bounds__(256)
__global__ void attn_scan(float* __restrict__ st) {
  const int bh = blockIdx.x;
  for (int j = threadIdx.x; j < STS; j += 256) {
    float run = 0.f;
    for (int c = 0; c < NC; ++c) {
      const size_t o = ((size_t)(bh * NC + c)) * STS + j;
      const float v = st[o];
      st[o] = run;
      run += v;
    }
  }
}

// ---------------- pass 3: per-chunk output (inter via state + intra causal) ----------------
__launch_bounds__(256)
__global__ void attn_out(const float* __restrict__ Qt, const float* __restrict__ Kt,
                         const float* __restrict__ Vt, const float* __restrict__ st,
                         float* __restrict__ Ot) {
  __shared__ float Qs[CHK][D + 1];
  __shared__ float Ks2[CHK][D + 1];
  __shared__ float Vs2[CHK][D + 1];
  __shared__ float Ss[D][D + 1];
  __shared__ float ksx[D];
  const int bx = blockIdx.x;
  const int bh = bx / NC, c = bx % NC;
  const int tid = threadIdx.x;
  const size_t gbase = ((size_t)bh * L + (size_t)c * CHK) * D;
  for (int idx = tid; idx < CHK * D; idx += 256) {
    const int m = idx >> 6, d = idx & 63;
    Qs[m][d] = Qt[gbase + idx];
    Ks2[m][d] = Kt[gbase + idx];
    Vs2[m][d] = Vt[gbase + idx];
  }
  const float* stp = st + (size_t)bx * STS;
  for (int idx = tid; idx < D * D; idx += 256) Ss[idx >> 6][idx & 63] = stp[idx];
  if (tid < D) ksx[tid] = stp[D * D + tid];
  __syncthreads();
  const int n = tid >> 1, e0 = (tid & 1) * 32;
  float o[32];
#pragma unroll
  for (int e = 0; e < 32; ++e) o[e] = 0.f;
  float rowsum = 0.f;
  for (int d = 0; d < D; ++d) {
    const float qd = Qs[n][d];
    rowsum += qd * ksx[d];
#pragma unroll
    for (int e = 0; e < 32; ++e) o[e] += qd * Ss[d][e0 + e];
  }
  for (int m = 0; m <= n; ++m) {
    float s = 0.f;
#pragma unroll
    for (int d = 0; d < D; ++d) s += Qs[n][d] * Ks2[m][d];
    rowsum += s;
#pragma unroll
    for (int e = 0; e < 32; ++e) o[e] += s * Vs2[m][e0 + e];
  }
  const float inv = 1.f / fmaxf(rowsum, EPS);
  const int nglob = c * CHK + n;
  const int b = bh >> 4, h = bh & 15; // bh = b*H + h
  float* op = Ot + ((size_t)nglob * Bb + b) * E + (size_t)h * D + e0;
#pragma unroll
  for (int e = 0; e < 32; ++e) op[e] = o[e] * inv;
}

} // namespace

extern "C" void kernel_launch(void* const* d_in, const int* in_sizes, int n_in,
                              void* d_out, int out_size, void* d_ws, size_t ws_size,
                              hipStream_t stream) {
  (void)in_sizes; (void)n_in; (void)out_size; (void)ws_size;
  const float* query = (const float*)d_in[0];
  const float* key_  = (const float*)d_in[1];
  const float* value = (const float*)d_in[2];
  const float* q_w   = (const float*)d_in[3];
  const float* q_b   = (const float*)d_in[4];
  const float* k_w   = (const float*)d_in[5];
  const float* k_b   = (const float*)d_in[6];
  const float* v_w   = (const float*)d_in[7];
  const float* v_b   = (const float*)d_in[8];
  const float* out_w = (const float*)d_in[9];
  const float* out_b = (const float*)d_in[10];
  float* out = (float*)d_out;

  float* ws = (float*)d_ws;
  const size_t SZ = (size_t)M * E;        // 4,194,304 floats per f32 tensor
  float* q_ws = ws;                       // [0, 4M)
  float* k_ws = ws + SZ;                  // [4M, 8M)
  float* v_ws = ws + 2 * SZ;              // [8M, 12M)
  float* o_ws = ws + 3 * SZ;              // [12M, 16M)
  float* st   = ws + 4 * SZ;              // [16M, 16M+2.13M)
  // A hi/lo (4M bf16 each = 16MB total) overlaps o_ws region [12M,16M):
  // dead before attn_out writes o_ws.
  bf16* Ahi = (bf16*)o_ws;
  bf16* Alo = (bf16*)(o_ws + SZ / 2);
  // W hi/lo (1M bf16 each) after st
  bf16* Whi = (bf16*)(st + STS * BH * NC);
  bf16* Wlo = Whi + (size_t)E * E;
  // o hi/lo for the output projection overlap q_ws (dead after attn_out)
  bf16* Ohi = (bf16*)q_ws;
  bf16* Olo = (bf16*)(q_ws + SZ / 2);

  const int n8A = (int)(SZ / 8);          // 524288
  const int n8W = E * E / 8;              // 131072
  const dim3 gg(E / GBN, M / GBM);        // (16, 32) = 512 blocks

  // q projection
  hipLaunchKernelGGL(split_conv, dim3(n8W / 256), dim3(256), 0, stream, q_w, Whi, Wlo, n8W);
  hipLaunchKernelGGL(split_conv, dim3(n8A / 256), dim3(256), 0, stream, query, Ahi, Alo, n8A);
  hipLaunchKernelGGL((gemm_split<1>), gg, dim3(256), 0, stream, Ahi, Alo, Whi, Wlo, q_b, q_ws);
  // k projection
  hipLaunchKernelGGL(split_conv, dim3(n8W / 256), dim3(256), 0, stream, k_w, Whi, Wlo, n8W);
  hipLaunchKernelGGL(split_conv, dim3(n8A / 256), dim3(256), 0, stream, key_, Ahi, Alo, n8A);
  hipLaunchKernelGGL((gemm_split<1>), gg, dim3(256), 0, stream, Ahi, Alo, Whi, Wlo, k_b, k_ws);
  // v projection
  hipLaunchKernelGGL(split_conv, dim3(n8W / 256), dim3(256), 0, stream, v_w, Whi, Wlo, n8W);
  hipLaunchKernelGGL(split_conv, dim3(n8A / 256), dim3(256), 0, stream, value, Ahi, Alo, n8A);
  hipLaunchKernelGGL((gemm_split<1>), gg, dim3(256), 0, stream, Ahi, Alo, Whi, Wlo, v_b, v_ws);
  // attention
  hipLaunchKernelGGL(relu_rope, dim3(2 * BH * L * (D / 2) / 256), dim3(256), 0, stream, q_ws, k_ws);
  hipLaunchKernelGGL(attn_state, dim3(BH * NC), dim3(256), 0, stream, k_ws, v_ws, st);
  hipLaunchKernelGGL(attn_scan, dim3(BH), dim3(256), 0, stream, st);
  hipLaunchKernelGGL(attn_out, dim3(BH * NC), dim3(256), 0, stream, q_ws, k_ws, v_ws, st, o_ws);
  // output projection
  hipLaunchKernelGGL(split_conv, dim3(n8W / 256), dim3(256), 0, stream, out_w, Whi, Wlo, n8W);
  hipLaunchKernelGGL(split_conv, dim3(n8A / 256), dim3(256), 0, stream, o_ws, Ohi, Olo, n8A);
  hipLaunchKernelGGL((gemm_split<0>), gg, dim3(256), 0, stream, Ohi, Olo, Whi, Wlo, out_b, out);
}

// Round 4
// 255.090 us; speedup vs baseline: 4.4943x; 1.6391x over previous
//
#include <hip/hip_runtime.h>

namespace {

constexpr int L = 2048, Bb = 2, E = 1024, H = 16, D = 64;
constexpr int M = L * Bb;              // 4096 rows (l*B + b)
constexpr int CHK = 64, NC = L / CHK;  // 32 chunks of 64
constexpr int BH = Bb * H;             // 32
constexpr int STSZ = 65 * 64;          // S^T (64x64) + ksum row, per chunk
constexpr float EPS = 1e-4f;

using bf16 = __bf16;
typedef __attribute__((ext_vector_type(8))) __bf16 bf16x8;
typedef __attribute__((ext_vector_type(4))) __bf16 bf16x4;
typedef __attribute__((ext_vector_type(4))) float f32x4;

#define GLDS16(ldsdst, gsrc)                                      \
  __builtin_amdgcn_global_load_lds(                               \
      (const __attribute__((address_space(1))) void*)(gsrc),      \
      (__attribute__((address_space(3))) void*)(ldsdst), 16, 0, 0)

__device__ __forceinline__ void split2(float v, bf16& h, bf16& l) {
  h = (bf16)v;
  l = (bf16)(v - (float)h);
}

// ---------------- f32 -> bf16 hi/lo split (8 elements / thread) ----------------
__launch_bounds__(256)
__global__ void split_conv(const float* __restrict__ x, bf16* __restrict__ hi,
                           bf16* __restrict__ lo, int n8) {
  const int idx = blockIdx.x * 256 + threadIdx.x;
  if (idx >= n8) return;
  const float4* p = reinterpret_cast<const float4*>(x) + (size_t)idx * 2;
  const float4 a = p[0], b = p[1];
  const float v[8] = {a.x, a.y, a.z, a.w, b.x, b.y, b.z, b.w};
  bf16x8 h, l;
#pragma unroll
  for (int j = 0; j < 8; ++j) {
    const bf16 hb = (bf16)v[j];
    h[j] = hb;
    l[j] = (bf16)(v[j] - (float)hb);
  }
  *reinterpret_cast<bf16x8*>(hi + (size_t)idx * 8) = h;
  *reinterpret_cast<bf16x8*>(lo + (size_t)idx * 8) = l;
}

// ------------- split-bf16 MFMA GEMM:  C = A(4096x1024) * W(1024x1024)^T + bias -------------
constexpr int GBM = 128, GBN = 64, GBK = 32;

template <int MODE>
__launch_bounds__(256)
__global__ void gemm_split(const bf16* __restrict__ Ahi, const bf16* __restrict__ Alo,
                           const bf16* __restrict__ Whi, const bf16* __restrict__ Wlo,
                           const float* __restrict__ bias, float* __restrict__ Cdst) {
  __shared__ __align__(16) unsigned short sAhi[GBM * GBK];
  __shared__ __align__(16) unsigned short sAlo[GBM * GBK];
  __shared__ __align__(16) unsigned short sBhi[GBN * GBK];
  __shared__ __align__(16) unsigned short sBlo[GBN * GBK];
  const int tid = threadIdx.x;
  const int row0 = blockIdx.y * GBM, col0 = blockIdx.x * GBN;
  const int lane = tid & 63, wid = tid >> 6;
  const int wr = wid >> 1, wc = wid & 1;       // 2x2 waves; wave tile 64x32
  const int fr = lane & 15, kg = lane >> 4;
  f32x4 acc[4][2] = {};

  const int lin = tid * 8;
  const int ar0 = lin >> 5, ac0 = lin & 31;
  const int ar1 = (lin + 2048) >> 5;

  const size_t K = E;
  for (int kt = 0; kt < E; kt += GBK) {
    GLDS16(&sAhi[lin],        Ahi + (size_t)(row0 + ar0) * K + kt + ac0);
    GLDS16(&sAhi[lin + 2048], Ahi + (size_t)(row0 + ar1) * K + kt + ac0);
    GLDS16(&sAlo[lin],        Alo + (size_t)(row0 + ar0) * K + kt + ac0);
    GLDS16(&sAlo[lin + 2048], Alo + (size_t)(row0 + ar1) * K + kt + ac0);
    GLDS16(&sBhi[lin],        Whi + (size_t)(col0 + ar0) * K + kt + ac0);
    GLDS16(&sBlo[lin],        Wlo + (size_t)(col0 + ar0) * K + kt + ac0);
    __syncthreads();

    bf16x8 ah[4], al[4], bh[2], bl[2];
#pragma unroll
    for (int m = 0; m < 4; ++m) {
      const int off = (wr * 64 + m * 16 + fr) * GBK + kg * 8;
      ah[m] = *reinterpret_cast<const bf16x8*>(&sAhi[off]);
      al[m] = *reinterpret_cast<const bf16x8*>(&sAlo[off]);
    }
#pragma unroll
    for (int n = 0; n < 2; ++n) {
      const int off = (wc * 32 + n * 16 + fr) * GBK + kg * 8;
      bh[n] = *reinterpret_cast<const bf16x8*>(&sBhi[off]);
      bl[n] = *reinterpret_cast<const bf16x8*>(&sBlo[off]);
    }
#pragma unroll
    for (int m = 0; m < 4; ++m)
#pragma unroll
      for (int n = 0; n < 2; ++n) {
        acc[m][n] = __builtin_amdgcn_mfma_f32_16x16x32_bf16(ah[m], bh[n], acc[m][n], 0, 0, 0);
        acc[m][n] = __builtin_amdgcn_mfma_f32_16x16x32_bf16(ah[m], bl[n], acc[m][n], 0, 0, 0);
        acc[m][n] = __builtin_amdgcn_mfma_f32_16x16x32_bf16(al[m], bh[n], acc[m][n], 0, 0, 0);
      }
    __syncthreads();
  }

#pragma unroll
  for (int m = 0; m < 4; ++m) {
    const int rbase = row0 + wr * 64 + m * 16 + kg * 4;
#pragma unroll
    for (int n = 0; n < 2; ++n) {
      const int c = col0 + wc * 32 + n * 16 + fr;
      const float bia = bias[c];
#pragma unroll
      for (int i = 0; i < 4; ++i) {
        const float v = acc[m][n][i] + bia;
        const int r = rbase + i;
        if (MODE == 0) {
          Cdst[(size_t)r * E + c] = v;
        } else {
          const int nn = r >> 1, b = r & 1;
          const int h = c >> 6, dd = c & 63;
          Cdst[(((size_t)(b * H + h)) * L + nn) * D + dd] = v;
        }
      }
    }
  }
}

// ---------------- relu + interleaved RoPE (in place, (bh,n,d) layout) ----------------
__launch_bounds__(256)
__global__ void relu_rope(float* __restrict__ q, float* __restrict__ k) {
  const size_t total = (size_t)BH * L * (D / 2);
  size_t idx = (size_t)blockIdx.x * 256 + threadIdx.x;
  float* p = q;
  if (idx >= total) { p = k; idx -= total; }
  const int i = (int)(idx & 31);
  const int n = (int)((idx >> 5) & (L - 1));
  const size_t bh = idx >> 16;
  const size_t base = (bh * L + n) * D + 2 * i;
  const float theta = expf(-(float)i * 0.2878231366242557f); // 10000^(-i/32)
  float s, c;
  sincosf((float)n * theta, &s, &c);
  const float x0 = fmaxf(p[base], 0.f);
  const float x1 = fmaxf(p[base + 1], 0.f);
  p[base] = x0 * c - x1 * s;
  p[base + 1] = x0 * s + x1 * c;
}

// ---- pass 1 (MFMA): per-chunk S^T_ext = V^T_ext(80x64) . K(64x64) -> st[65][64] ----
// V^T_ext rows: 0..63 = V^T, 64 = ones (-> ksum row), 65..79 = 0.
__launch_bounds__(256)
__global__ void attn_state(const float* __restrict__ Kt, const float* __restrict__ Vt,
                           float* __restrict__ st) {
  __shared__ bf16 sVh[80 * 64], sVl[80 * 64];  // V^T_ext
  __shared__ bf16 sKh[64 * 64], sKl[64 * 64];  // K^T (rows d, cols m)
  const int bx = blockIdx.x;
  const int bh = bx / NC, c = bx % NC;
  const int tid = threadIdx.x;
  const size_t gbase = ((size_t)bh * L + (size_t)c * CHK) * D;

  for (int i = tid; i < 1024; i += 256) {          // 1024 float4 = 64 rows x 16
    const int m = i >> 4, c4 = (i & 15) * 4;
    const float4 kv = *reinterpret_cast<const float4*>(Kt + gbase + i * 4);
    const float4 vv = *reinterpret_cast<const float4*>(Vt + gbase + i * 4);
    const float ka[4] = {kv.x, kv.y, kv.z, kv.w};
    const float va[4] = {vv.x, vv.y, vv.z, vv.w};
#pragma unroll
    for (int j = 0; j < 4; ++j) {
      bf16 h, l;
      split2(ka[j], h, l);
      sKh[(c4 + j) * 64 + m] = h; sKl[(c4 + j) * 64 + m] = l;   // K^T[d][m]
      split2(va[j], h, l);
      sVh[(c4 + j) * 64 + m] = h; sVl[(c4 + j) * 64 + m] = l;   // V^T[e][m]
    }
  }
  for (int i = tid; i < 16 * 64; i += 256) {       // ext rows 64..79
    const int r = 64 + (i >> 6), cc = i & 63;
    sVh[r * 64 + cc] = (r == 64) ? (bf16)1.0f : (bf16)0.0f;
    sVl[r * 64 + cc] = (bf16)0.0f;
  }
  __syncthreads();

  const int w = tid >> 6, lane = tid & 63;
  const int fr = lane & 15, kg = lane >> 4;
  f32x4 acc[5] = {};
#pragma unroll
  for (int ks = 0; ks < 2; ++ks) {
    const int boff = (w * 16 + fr) * 64 + ks * 32 + kg * 8;
    const bf16x8 bh_ = *reinterpret_cast<const bf16x8*>(&sKh[boff]);
    const bf16x8 bl_ = *reinterpret_cast<const bf16x8*>(&sKl[boff]);
#pragma unroll
    for (int rt = 0; rt < 5; ++rt) {
      const int aoff = (rt * 16 + fr) * 64 + ks * 32 + kg * 8;
      const bf16x8 ah = *reinterpret_cast<const bf16x8*>(&sVh[aoff]);
      const bf16x8 al = *reinterpret_cast<const bf16x8*>(&sVl[aoff]);
      acc[rt] = __builtin_amdgcn_mfma_f32_16x16x32_bf16(ah, bh_, acc[rt], 0, 0, 0);
      acc[rt] = __builtin_amdgcn_mfma_f32_16x16x32_bf16(ah, bl_, acc[rt], 0, 0, 0);
      acc[rt] = __builtin_amdgcn_mfma_f32_16x16x32_bf16(al, bh_, acc[rt], 0, 0, 0);
    }
  }
  float* stp = st + (size_t)bx * STSZ;
#pragma unroll
  for (int rt = 0; rt < 5; ++rt)
#pragma unroll
    for (int i = 0; i < 4; ++i) {
      const int e = rt * 16 + kg * 4 + i;
      if (e < 65) stp[e * 64 + w * 16 + fr] = acc[rt][i];
    }
}

// ---------------- pass 2: exclusive prefix scan over chunks (elementwise) ----------------
__launch_bounds__(256)
__global__ void attn_scan(float* __restrict__ st) {
  const int bh = blockIdx.x;
  const int j = blockIdx.y * 256 + threadIdx.x;
  if (j >= STSZ) return;
  float run = 0.f;
  for (int c = 0; c < NC; ++c) {
    const size_t o = ((size_t)(bh * NC + c)) * STSZ + j;
    const float v = st[o];
    st[o] = run;
    run += v;
  }
}

// ---- pass 3 (MFMA fused): W=QK^T (causal) ; O = W~ V + Q S_excl ; rowsum via ones/ksum cols ----
__launch_bounds__(256)
__global__ void attn_out(const float* __restrict__ Qt, const float* __restrict__ Kt,
                         const float* __restrict__ Vt, const float* __restrict__ st,
                         float* __restrict__ Ot) {
  __shared__ bf16 sQh[64 * 64], sQl[64 * 64];
  __shared__ bf16 sKWh[64 * 64], sKWl[64 * 64];  // K (phase1) then W~ (phase2)
  __shared__ bf16 sVh[80 * 64], sVl[80 * 64];    // V^T_ext (row64 = ones)
  __shared__ bf16 sSh[80 * 64], sSl[80 * 64];    // S^T_ext (row64 = ksum_excl)
  const int bx = blockIdx.x;
  const int bh = bx / NC, c = bx % NC;
  const int tid = threadIdx.x;
  const size_t gbase = ((size_t)bh * L + (size_t)c * CHK) * D;

  // stage Q, K row-major; V transposed
  for (int i = tid; i < 1024; i += 256) {
    const float4 qv = *reinterpret_cast<const float4*>(Qt + gbase + i * 4);
    const float4 kv = *reinterpret_cast<const float4*>(Kt + gbase + i * 4);
    const float4 vv = *reinterpret_cast<const float4*>(Vt + gbase + i * 4);
    const float qa[4] = {qv.x, qv.y, qv.z, qv.w};
    const float ka[4] = {kv.x, kv.y, kv.z, kv.w};
    const float va[4] = {vv.x, vv.y, vv.z, vv.w};
    bf16x4 qh, ql, kh, kl;
    const int m = i >> 4, c4 = (i & 15) * 4;
#pragma unroll
    for (int j = 0; j < 4; ++j) {
      bf16 th, tl;
      split2(qa[j], th, tl); qh[j] = th; ql[j] = tl;
      split2(ka[j], th, tl); kh[j] = th; kl[j] = tl;
      split2(va[j], th, tl);
      sVh[(c4 + j) * 64 + m] = th; sVl[(c4 + j) * 64 + m] = tl;
    }
    *reinterpret_cast<bf16x4*>(&sQh[i * 4]) = qh;
    *reinterpret_cast<bf16x4*>(&sQl[i * 4]) = ql;
    *reinterpret_cast<bf16x4*>(&sKWh[i * 4]) = kh;
    *reinterpret_cast<bf16x4*>(&sKWl[i * 4]) = kl;
  }
  const float* stp = st + (size_t)(bh * NC + c) * STSZ;
  for (int i = tid; i < 1040; i += 256) {          // 65*64/4 f4 of scanned state
    const float4 sv = *reinterpret_cast<const float4*>(stp + i * 4);
    const float sa[4] = {sv.x, sv.y, sv.z, sv.w};
    bf16x4 h4, l4;
#pragma unroll
    for (int j = 0; j < 4; ++j) {
      bf16 th, tl;
      split2(sa[j], th, tl);
      h4[j] = th; l4[j] = tl;
    }
    *reinterpret_cast<bf16x4*>(&sSh[i * 4]) = h4;
    *reinterpret_cast<bf16x4*>(&sSl[i * 4]) = l4;
  }
  for (int i = tid; i < 16 * 64; i += 256) {       // ext rows 64..79
    const int r = 64 + (i >> 6), cc = i & 63;
    sVh[r * 64 + cc] = (r == 64) ? (bf16)1.0f : (bf16)0.0f;
    sVl[r * 64 + cc] = (bf16)0.0f;
    if (r > 64) { sSh[r * 64 + cc] = (bf16)0.0f; sSl[r * 64 + cc] = (bf16)0.0f; }
  }
  __syncthreads();

  const int w = tid >> 6, lane = tid & 63;
  const int fr = lane & 15, kg = lane >> 4;
  f32x4 Wacc[4] = {};
  f32x4 Oacc[5] = {};

  // phase 1a: W = Q K^T for row band w (tiles t <= w only)
#pragma unroll
  for (int ks = 0; ks < 2; ++ks) {
    const int aoff = (w * 16 + fr) * 64 + ks * 32 + kg * 8;
    const bf16x8 ah = *reinterpret_cast<const bf16x8*>(&sQh[aoff]);
    const bf16x8 al = *reinterpret_cast<const bf16x8*>(&sQl[aoff]);
    for (int t = 0; t <= w; ++t) {
      const int boff = (t * 16 + fr) * 64 + ks * 32 + kg * 8;
      const bf16x8 bh_ = *reinterpret_cast<const bf16x8*>(&sKWh[boff]);
      const bf16x8 bl_ = *reinterpret_cast<const bf16x8*>(&sKWl[boff]);
      Wacc[t] = __builtin_amdgcn_mfma_f32_16x16x32_bf16(ah, bh_, Wacc[t], 0, 0, 0);
      Wacc[t] = __builtin_amdgcn_mfma_f32_16x16x32_bf16(ah, bl_, Wacc[t], 0, 0, 0);
      Wacc[t] = __builtin_amdgcn_mfma_f32_16x16x32_bf16(al, bh_, Wacc[t], 0, 0, 0);
    }
    // phase 1b: O += Q . S^T_ext (inter-chunk; col-tile 4 row 64 = ksum -> rowsum_inter)
#pragma unroll
    for (int ct = 0; ct < 5; ++ct) {
      const int soff = (ct * 16 + fr) * 64 + ks * 32 + kg * 8;
      const bf16x8 sh = *reinterpret_cast<const bf16x8*>(&sSh[soff]);
      const bf16x8 sl = *reinterpret_cast<const bf16x8*>(&sSl[soff]);
      Oacc[ct] = __builtin_amdgcn_mfma_f32_16x16x32_bf16(ah, sh, Oacc[ct], 0, 0, 0);
      Oacc[ct] = __builtin_amdgcn_mfma_f32_16x16x32_bf16(ah, sl, Oacc[ct], 0, 0, 0);
      Oacc[ct] = __builtin_amdgcn_mfma_f32_16x16x32_bf16(al, sh, Oacc[ct], 0, 0, 0);
    }
  }
  __syncthreads();  // all K reads done before W~ overwrite

  // mask + split W~ into sKW (rows n, cols m)
#pragma unroll
  for (int t = 0; t < 4; ++t)
#pragma unroll
    for (int i = 0; i < 4; ++i) {
      const int n_loc = w * 16 + kg * 4 + i;
      const int m_loc = t * 16 + fr;
      const float v = (m_loc <= n_loc) ? Wacc[t][i] : 0.f;
      bf16 h, l;
      split2(v, h, l);
      sKWh[n_loc * 64 + m_loc] = h;
      sKWl[n_loc * 64 + m_loc] = l;
    }
  __syncthreads();

  // phase 2: O += W~ . V^T_ext (col 64 -> rowsum_intra)
  const int kmax = (w < 2) ? 1 : 2;                // W~ cols m > band max are zero
  for (int ks = 0; ks < kmax; ++ks) {
    const int aoff = (w * 16 + fr) * 64 + ks * 32 + kg * 8;
    const bf16x8 ah = *reinterpret_cast<const bf16x8*>(&sKWh[aoff]);
    const bf16x8 al = *reinterpret_cast<const bf16x8*>(&sKWl[aoff]);
#pragma unroll
    for (int ct = 0; ct < 5; ++ct) {
      const int boff = (ct * 16 + fr) * 64 + ks * 32 + kg * 8;
      const bf16x8 bh_ = *reinterpret_cast<const bf16x8*>(&sVh[boff]);
      const bf16x8 bl_ = *reinterpret_cast<const bf16x8*>(&sVl[boff]);
      Oacc[ct] = __builtin_amdgcn_mfma_f32_16x16x32_bf16(ah, bh_, Oacc[ct], 0, 0, 0);
      Oacc[ct] = __builtin_amdgcn_mfma_f32_16x16x32_bf16(ah, bl_, Oacc[ct], 0, 0, 0);
      Oacc[ct] = __builtin_amdgcn_mfma_f32_16x16x32_bf16(al, bh_, Oacc[ct], 0, 0, 0);
    }
  }

  // rowsum = sum over fr-lanes of Oacc[4] (cols 65..79 are exact zeros)
  float inv[4];
#pragma unroll
  for (int i = 0; i < 4; ++i) {
    float r = Oacc[4][i];
    r += __shfl_xor(r, 1);
    r += __shfl_xor(r, 2);
    r += __shfl_xor(r, 4);
    r += __shfl_xor(r, 8);
    inv[i] = 1.f / fmaxf(r, EPS);
  }

  const int b = bh >> 4, h = bh & 15;
#pragma unroll
  for (int i = 0; i < 4; ++i) {
    const int nglob = c * CHK + w * 16 + kg * 4 + i;
    float* op = Ot + ((size_t)nglob * Bb + b) * E + (size_t)h * D;
#pragma unroll
    for (int t = 0; t < 4; ++t) op[t * 16 + fr] = Oacc[t][i] * inv[i];
  }
}

} // namespace

extern "C" void kernel_launch(void* const* d_in, const int* in_sizes, int n_in,
                              void* d_out, int out_size, void* d_ws, size_t ws_size,
                              hipStream_t stream) {
  (void)in_sizes; (void)n_in; (void)out_size; (void)ws_size;
  const float* query = (const float*)d_in[0];
  const float* key_  = (const float*)d_in[1];
  const float* value = (const float*)d_in[2];
  const float* q_w   = (const float*)d_in[3];
  const float* q_b   = (const float*)d_in[4];
  const float* k_w   = (const float*)d_in[5];
  const float* k_b   = (const float*)d_in[6];
  const float* v_w   = (const float*)d_in[7];
  const float* v_b   = (const float*)d_in[8];
  const float* out_w = (const float*)d_in[9];
  const float* out_b = (const float*)d_in[10];
  float* out = (float*)d_out;

  float* ws = (float*)d_ws;
  const size_t SZ = (size_t)M * E;        // 4,194,304 floats per f32 tensor
  float* q_ws = ws;
  float* k_ws = ws + SZ;
  float* v_ws = ws + 2 * SZ;
  float* o_ws = ws + 3 * SZ;
  float* st   = ws + 4 * SZ;              // 32*32*4160 floats
  bf16* Ahi = (bf16*)o_ws;                // dead before attn_out writes o_ws
  bf16* Alo = (bf16*)(o_ws + SZ / 2);
  bf16* Whi = (bf16*)(st + (size_t)STSZ * BH * NC);
  bf16* Wlo = Whi + (size_t)E * E;
  bf16* Ohi = (bf16*)q_ws;                // q_ws dead after attn_out
  bf16* Olo = (bf16*)(q_ws + SZ / 2);

  const int n8A = (int)(SZ / 8);
  const int n8W = E * E / 8;
  const dim3 gg(E / GBN, M / GBM);        // (16, 32)

  hipLaunchKernelGGL(split_conv, dim3(n8W / 256), dim3(256), 0, stream, q_w, Whi, Wlo, n8W);
  hipLaunchKernelGGL(split_conv, dim3(n8A / 256), dim3(256), 0, stream, query, Ahi, Alo, n8A);
  hipLaunchKernelGGL((gemm_split<1>), gg, dim3(256), 0, stream, Ahi, Alo, Whi, Wlo, q_b, q_ws);
  hipLaunchKernelGGL(split_conv, dim3(n8W / 256), dim3(256), 0, stream, k_w, Whi, Wlo, n8W);
  hipLaunchKernelGGL(split_conv, dim3(n8A / 256), dim3(256), 0, stream, key_, Ahi, Alo, n8A);
  hipLaunchKernelGGL((gemm_split<1>), gg, dim3(256), 0, stream, Ahi, Alo, Whi, Wlo, k_b, k_ws);
  hipLaunchKernelGGL(split_conv, dim3(n8W / 256), dim3(256), 0, stream, v_w, Whi, Wlo, n8W);
  hipLaunchKernelGGL(split_conv, dim3(n8A / 256), dim3(256), 0, stream, value, Ahi, Alo, n8A);
  hipLaunchKernelGGL((gemm_split<1>), gg, dim3(256), 0, stream, Ahi, Alo, Whi, Wlo, v_b, v_ws);

  hipLaunchKernelGGL(relu_rope, dim3(2 * BH * L * (D / 2) / 256), dim3(256), 0, stream, q_ws, k_ws);
  hipLaunchKernelGGL(attn_state, dim3(BH * NC), dim3(256), 0, stream, k_ws, v_ws, st);
  hipLaunchKernelGGL(attn_scan, dim3(BH, (STSZ + 255) / 256), dim3(256), 0, stream, st);
  hipLaunchKernelGGL(attn_out, dim3(BH * NC), dim3(256), 0, stream, q_ws, k_ws, v_ws, st, o_ws);

  hipLaunchKernelGGL(split_conv, dim3(n8W / 256), dim3(256), 0, stream, out_w, Whi, Wlo, n8W);
  hipLaunchKernelGGL(split_conv, dim3(n8A / 256), dim3(256), 0, stream, o_ws, Ohi, Olo, n8A);
  hipLaunchKernelGGL((gemm_split<0>), gg, dim3(256), 0, stream, Ohi, Olo, Whi, Wlo, out_b, out);
}

// Round 5
// 232.045 us; speedup vs baseline: 4.9407x; 1.0993x over previous
//
#include <hip/hip_runtime.h>

namespace {

constexpr int L = 2048, Bb = 2, E = 1024, H = 16, D = 64;
constexpr int M = L * Bb;              // 4096 rows (l*B + b)
constexpr int CHK = 64, NC = L / CHK;  // 32 chunks of 64
constexpr int BH = Bb * H;             // 32
constexpr int STSZ = 65 * 64;          // S^T (64x64) + ksum row, per chunk
constexpr float EPS = 1e-4f;

using bf16 = __bf16;
typedef __attribute__((ext_vector_type(8))) __bf16 bf16x8;
typedef __attribute__((ext_vector_type(4))) __bf16 bf16x4;
typedef __attribute__((ext_vector_type(4))) float f32x4;

#define GLDS16(ldsdst, gsrc)                                      \
  __builtin_amdgcn_global_load_lds(                               \
      (const __attribute__((address_space(1))) void*)(gsrc),      \
      (__attribute__((address_space(3))) void*)(ldsdst), 16, 0, 0)

// compiler-level fence around raw s_barrier: memory ops cannot cross;
// hardware waits are done manually via counted vmcnt (T4 pattern).
#define BARRIER_NODRAIN()                      \
  do {                                         \
    asm volatile("" ::: "memory");             \
    __builtin_amdgcn_s_barrier();              \
    asm volatile("" ::: "memory");             \
  } while (0)

__device__ __forceinline__ void split2(float v, bf16& h, bf16& l) {
  h = (bf16)v;
  l = (bf16)(v - (float)h);
}

// -------- f32 -> bf16 hi/lo split for one A tensor + one W tensor, single dispatch --------
__launch_bounds__(256)
__global__ void split_conv2(const float* __restrict__ a, bf16* __restrict__ ahi,
                            bf16* __restrict__ alo, int n8a,
                            const float* __restrict__ w, bf16* __restrict__ whi,
                            bf16* __restrict__ wlo, int n8w) {
  int idx = blockIdx.x * 256 + threadIdx.x;
  const float* src;
  bf16 *hi, *lo;
  if (idx < n8a) {
    src = a; hi = ahi; lo = alo;
  } else {
    idx -= n8a;
    if (idx >= n8w) return;
    src = w; hi = whi; lo = wlo;
  }
  const float4* p = reinterpret_cast<const float4*>(src) + (size_t)idx * 2;
  const float4 x = p[0], y = p[1];
  const float v[8] = {x.x, x.y, x.z, x.w, y.x, y.y, y.z, y.w};
  bf16x8 h, l;
#pragma unroll
  for (int j = 0; j < 8; ++j) {
    const bf16 hb = (bf16)v[j];
    h[j] = hb;
    l[j] = (bf16)(v[j] - (float)hb);
  }
  *reinterpret_cast<bf16x8*>(hi + (size_t)idx * 8) = h;
  *reinterpret_cast<bf16x8*>(lo + (size_t)idx * 8) = l;
}

// ------------- split-bf16 MFMA GEMM, double-buffered prefetch -------------
// C = A(4096x1024) * W(1024x1024)^T + bias  via hi*hi + hi*lo + lo*hi.
// MODE 0: C row-major. MODE 1: scatter to (b,h,n,d); ROPE: relu+URPE in epilogue.
constexpr int GBM = 128, GBN = 64, GBK = 32, NIT = E / GBK;

template <int MODE, bool ROPE>
__launch_bounds__(256, 2)
__global__ void gemm_split(const bf16* __restrict__ Ahi, const bf16* __restrict__ Alo,
                           const bf16* __restrict__ Whi, const bf16* __restrict__ Wlo,
                           const float* __restrict__ bias, float* __restrict__ Cdst) {
  __shared__ __align__(16) unsigned short sA[2][2][GBM * GBK];  // [buf][hi/lo]
  __shared__ __align__(16) unsigned short sB[2][2][GBN * GBK];
  const int tid = threadIdx.x;
  const int row0 = blockIdx.y * GBM, col0 = blockIdx.x * GBN;
  const int lane = tid & 63, wid = tid >> 6;
  const int wr = wid >> 1, wc = wid & 1;       // 2x2 waves; wave tile 64x32
  const int fr = lane & 15, kg = lane >> 4;
  f32x4 acc[4][2] = {};

  const int lin = tid * 8;                     // staging element index
  const int ar0 = lin >> 5, ac0 = lin & 31;    // tile row 0..63, col
  const int ar1 = ar0 + 64;                    // A rows 64..127

#define STAGE(b_, kt_)                                                          \
  do {                                                                          \
    GLDS16(&sA[b_][0][lin],        Ahi + (size_t)(row0 + ar0) * E + (kt_) + ac0); \
    GLDS16(&sA[b_][0][lin + 2048], Ahi + (size_t)(row0 + ar1) * E + (kt_) + ac0); \
    GLDS16(&sA[b_][1][lin],        Alo + (size_t)(row0 + ar0) * E + (kt_) + ac0); \
    GLDS16(&sA[b_][1][lin + 2048], Alo + (size_t)(row0 + ar1) * E + (kt_) + ac0); \
    GLDS16(&sB[b_][0][lin],        Whi + (size_t)(col0 + ar0) * E + (kt_) + ac0); \
    GLDS16(&sB[b_][1][lin],        Wlo + (size_t)(col0 + ar0) * E + (kt_) + ac0); \
  } while (0)

  STAGE(0, 0);
  int cur = 0;
  for (int t = 0; t < NIT; ++t) {
    if (t + 1 < NIT) {
      STAGE(cur ^ 1, (t + 1) * GBK);
      asm volatile("s_waitcnt vmcnt(6)" ::: "memory");  // current tile's 6 landed
    } else {
      asm volatile("s_waitcnt vmcnt(0)" ::: "memory");
    }
    BARRIER_NODRAIN();   // all waves' stages for buf[cur] visible

    bf16x8 ah[4], al[4], bh[2], bl[2];
#pragma unroll
    for (int m = 0; m < 4; ++m) {
      const int off = (wr * 64 + m * 16 + fr) * GBK + kg * 8;
      ah[m] = *reinterpret_cast<const bf16x8*>(&sA[cur][0][off]);
      al[m] = *reinterpret_cast<const bf16x8*>(&sA[cur][1][off]);
    }
#pragma unroll
    for (int n = 0; n < 2; ++n) {
      const int off = (wc * 32 + n * 16 + fr) * GBK + kg * 8;
      bh[n] = *reinterpret_cast<const bf16x8*>(&sB[cur][0][off]);
      bl[n] = *reinterpret_cast<const bf16x8*>(&sB[cur][1][off]);
    }
#pragma unroll
    for (int m = 0; m < 4; ++m)
#pragma unroll
      for (int n = 0; n < 2; ++n) {
        acc[m][n] = __builtin_amdgcn_mfma_f32_16x16x32_bf16(ah[m], bh[n], acc[m][n], 0, 0, 0);
        acc[m][n] = __builtin_amdgcn_mfma_f32_16x16x32_bf16(ah[m], bl[n], acc[m][n], 0, 0, 0);
        acc[m][n] = __builtin_amdgcn_mfma_f32_16x16x32_bf16(al[m], bh[n], acc[m][n], 0, 0, 0);
      }
    BARRIER_NODRAIN();   // reads of buf[cur] done before next iter overwrites it
    cur ^= 1;
  }
#undef STAGE

  // epilogue: C/D frag layout col=lane&15, row=(lane>>4)*4+i
#pragma unroll
  for (int m = 0; m < 4; ++m) {
    const int rbase = row0 + wr * 64 + m * 16 + kg * 4;
#pragma unroll
    for (int nn = 0; nn < 2; ++nn) {
      const int c = col0 + wc * 32 + nn * 16 + fr;
      const float bia = bias[c];
      float cs0 = 0.f, sn0 = 0.f, cs1 = 0.f, sn1 = 0.f;
      if (ROPE) {
        // theta_i = 10000^(-i/32), i = pair index within head
        const float theta = expf(-(float)((c & 63) >> 1) * 0.2878231366242557f);
        const int n0 = rbase >> 1;             // rbase multiple of 4
        sincosf((float)n0 * theta, &sn0, &cs0);
        sincosf((float)(n0 + 1) * theta, &sn1, &cs1);
      }
#pragma unroll
      for (int i = 0; i < 4; ++i) {
        float v = acc[m][nn][i] + bia;
        if (ROPE) {
          v = fmaxf(v, 0.f);
          const float p = __shfl_xor(v, 1);    // rope partner: col c^1, same row
          const float csv = (i < 2) ? cs0 : cs1;
          const float snv = (i < 2) ? sn0 : sn1;
          v = (c & 1) ? fmaf(p, snv, v * csv) : fmaf(-p, snv, v * csv);
        }
        const int r = rbase + i;
        if (MODE == 0) {
          Cdst[(size_t)r * E + c] = v;
        } else {
          const int nseq = r >> 1, b = r & 1;  // B = 2
          const int hh = c >> 6, dd = c & 63;  // D = 64
          Cdst[(((size_t)(b * H + hh)) * L + nseq) * D + dd] = v;
        }
      }
    }
  }
}

// ---- pass 1 (MFMA): per-chunk S^T_ext = V^T_ext(80x64) . K(64x64) -> st[65][64] ----
__launch_bounds__(256)
__global__ void attn_state(const float* __restrict__ Kt, const float* __restrict__ Vt,
                           float* __restrict__ st) {
  __shared__ bf16 sVh[80 * 64], sVl[80 * 64];  // V^T_ext (row 64 = ones)
  __shared__ bf16 sKh[64 * 64], sKl[64 * 64];  // K^T (rows d, cols m)
  const int bx = blockIdx.x;
  const int bh = bx / NC, c = bx % NC;
  const int tid = threadIdx.x;
  const size_t gbase = ((size_t)bh * L + (size_t)c * CHK) * D;

  for (int i = tid; i < 1024; i += 256) {
    const int m = i >> 4, c4 = (i & 15) * 4;
    const float4 kv = *reinterpret_cast<const float4*>(Kt + gbase + i * 4);
    const float4 vv = *reinterpret_cast<const float4*>(Vt + gbase + i * 4);
    const float ka[4] = {kv.x, kv.y, kv.z, kv.w};
    const float va[4] = {vv.x, vv.y, vv.z, vv.w};
#pragma unroll
    for (int j = 0; j < 4; ++j) {
      bf16 h, l;
      split2(ka[j], h, l);
      sKh[(c4 + j) * 64 + m] = h; sKl[(c4 + j) * 64 + m] = l;
      split2(va[j], h, l);
      sVh[(c4 + j) * 64 + m] = h; sVl[(c4 + j) * 64 + m] = l;
    }
  }
  for (int i = tid; i < 16 * 64; i += 256) {
    const int r = 64 + (i >> 6), cc = i & 63;
    sVh[r * 64 + cc] = (r == 64) ? (bf16)1.0f : (bf16)0.0f;
    sVl[r * 64 + cc] = (bf16)0.0f;
  }
  __syncthreads();

  const int w = tid >> 6, lane = tid & 63;
  const int fr = lane & 15, kg = lane >> 4;
  f32x4 acc[5] = {};
#pragma unroll
  for (int ks = 0; ks < 2; ++ks) {
    const int boff = (w * 16 + fr) * 64 + ks * 32 + kg * 8;
    const bf16x8 bh_ = *reinterpret_cast<const bf16x8*>(&sKh[boff]);
    const bf16x8 bl_ = *reinterpret_cast<const bf16x8*>(&sKl[boff]);
#pragma unroll
    for (int rt = 0; rt < 5; ++rt) {
      const int aoff = (rt * 16 + fr) * 64 + ks * 32 + kg * 8;
      const bf16x8 ah = *reinterpret_cast<const bf16x8*>(&sVh[aoff]);
      const bf16x8 al = *reinterpret_cast<const bf16x8*>(&sVl[aoff]);
      acc[rt] = __builtin_amdgcn_mfma_f32_16x16x32_bf16(ah, bh_, acc[rt], 0, 0, 0);
      acc[rt] = __builtin_amdgcn_mfma_f32_16x16x32_bf16(ah, bl_, acc[rt], 0, 0, 0);
      acc[rt] = __builtin_amdgcn_mfma_f32_16x16x32_bf16(al, bh_, acc[rt], 0, 0, 0);
    }
  }
  float* stp = st + (size_t)bx * STSZ;
#pragma unroll
  for (int rt = 0; rt < 5; ++rt)
#pragma unroll
    for (int i = 0; i < 4; ++i) {
      const int e = rt * 16 + kg * 4 + i;
      if (e < 65) stp[e * 64 + w * 16 + fr] = acc[rt][i];
    }
}

// ---------------- pass 2: exclusive prefix scan over chunks ----------------
__launch_bounds__(256)
__global__ void attn_scan(float* __restrict__ st) {
  const int bh = blockIdx.x;
  const int j = blockIdx.y * 256 + threadIdx.x;
  if (j >= STSZ) return;
  float run = 0.f;
  for (int c = 0; c < NC; ++c) {
    const size_t o = ((size_t)(bh * NC + c)) * STSZ + j;
    const float v = st[o];
    st[o] = run;
    run += v;
  }
}

// ---- pass 3 (MFMA fused): W=QK^T causal; O = W~ V + Q S_excl; rowsum via ones/ksum ----
// writes split bf16 O (hi/lo) directly for the output projection.
__launch_bounds__(256)
__global__ void attn_out(const float* __restrict__ Qt, const float* __restrict__ Kt,
                         const float* __restrict__ Vt, const float* __restrict__ st,
                         bf16* __restrict__ Ohi, bf16* __restrict__ Olo) {
  __shared__ bf16 sQh[64 * 64], sQl[64 * 64];
  __shared__ bf16 sKWh[64 * 64], sKWl[64 * 64];  // K (phase1) then W~ (phase2)
  __shared__ bf16 sVh[80 * 64], sVl[80 * 64];    // V^T_ext (row64 = ones)
  __shared__ bf16 sSh[80 * 64], sSl[80 * 64];    // S^T_ext (row64 = ksum_excl)
  const int bx = blockIdx.x;
  const int bh = bx / NC, c = bx % NC;
  const int tid = threadIdx.x;
  const size_t gbase = ((size_t)bh * L + (size_t)c * CHK) * D;

  for (int i = tid; i < 1024; i += 256) {
    const float4 qv = *reinterpret_cast<const float4*>(Qt + gbase + i * 4);
    const float4 kv = *reinterpret_cast<const float4*>(Kt + gbase + i * 4);
    const float4 vv = *reinterpret_cast<const float4*>(Vt + gbase + i * 4);
    const float qa[4] = {qv.x, qv.y, qv.z, qv.w};
    const float ka[4] = {kv.x, kv.y, kv.z, kv.w};
    const float va[4] = {vv.x, vv.y, vv.z, vv.w};
    bf16x4 qh, ql, kh, kl;
    const int m = i >> 4, c4 = (i & 15) * 4;
#pragma unroll
    for (int j = 0; j < 4; ++j) {
      bf16 th, tl;
      split2(qa[j], th, tl); qh[j] = th; ql[j] = tl;
      split2(ka[j], th, tl); kh[j] = th; kl[j] = tl;
      split2(va[j], th, tl);
      sVh[(c4 + j) * 64 + m] = th; sVl[(c4 + j) * 64 + m] = tl;
    }
    *reinterpret_cast<bf16x4*>(&sQh[i * 4]) = qh;
    *reinterpret_cast<bf16x4*>(&sQl[i * 4]) = ql;
    *reinterpret_cast<bf16x4*>(&sKWh[i * 4]) = kh;
    *reinterpret_cast<bf16x4*>(&sKWl[i * 4]) = kl;
  }
  const float* stp = st + (size_t)(bh * NC + c) * STSZ;
  for (int i = tid; i < 1040; i += 256) {
    const float4 sv = *reinterpret_cast<const float4*>(stp + i * 4);
    const float sa[4] = {sv.x, sv.y, sv.z, sv.w};
    bf16x4 h4, l4;
#pragma unroll
    for (int j = 0; j < 4; ++j) {
      bf16 th, tl;
      split2(sa[j], th, tl);
      h4[j] = th; l4[j] = tl;
    }
    *reinterpret_cast<bf16x4*>(&sSh[i * 4]) = h4;
    *reinterpret_cast<bf16x4*>(&sSl[i * 4]) = l4;
  }
  for (int i = tid; i < 16 * 64; i += 256) {
    const int r = 64 + (i >> 6), cc = i & 63;
    sVh[r * 64 + cc] = (r == 64) ? (bf16)1.0f : (bf16)0.0f;
    sVl[r * 64 + cc] = (bf16)0.0f;
    if (r > 64) { sSh[r * 64 + cc] = (bf16)0.0f; sSl[r * 64 + cc] = (bf16)0.0f; }
  }
  __syncthreads();

  const int w = tid >> 6, lane = tid & 63;
  const int fr = lane & 15, kg = lane >> 4;
  f32x4 Wacc[4] = {};
  f32x4 Oacc[5] = {};

#pragma unroll
  for (int ks = 0; ks < 2; ++ks) {
    const int aoff = (w * 16 + fr) * 64 + ks * 32 + kg * 8;
    const bf16x8 ah = *reinterpret_cast<const bf16x8*>(&sQh[aoff]);
    const bf16x8 al = *reinterpret_cast<const bf16x8*>(&sQl[aoff]);
    for (int t = 0; t <= w; ++t) {
      const int boff = (t * 16 + fr) * 64 + ks * 32 + kg * 8;
      const bf16x8 bh_ = *reinterpret_cast<const bf16x8*>(&sKWh[boff]);
      const bf16x8 bl_ = *reinterpret_cast<const bf16x8*>(&sKWl[boff]);
      Wacc[t] = __builtin_amdgcn_mfma_f32_16x16x32_bf16(ah, bh_, Wacc[t], 0, 0, 0);
      Wacc[t] = __builtin_amdgcn_mfma_f32_16x16x32_bf16(ah, bl_, Wacc[t], 0, 0, 0);
      Wacc[t] = __builtin_amdgcn_mfma_f32_16x16x32_bf16(al, bh_, Wacc[t], 0, 0, 0);
    }
#pragma unroll
    for (int ct = 0; ct < 5; ++ct) {
      const int soff = (ct * 16 + fr) * 64 + ks * 32 + kg * 8;
      const bf16x8 sh = *reinterpret_cast<const bf16x8*>(&sSh[soff]);
      const bf16x8 sl = *reinterpret_cast<const bf16x8*>(&sSl[soff]);
      Oacc[ct] = __builtin_amdgcn_mfma_f32_16x16x32_bf16(ah, sh, Oacc[ct], 0, 0, 0);
      Oacc[ct] = __builtin_amdgcn_mfma_f32_16x16x32_bf16(ah, sl, Oacc[ct], 0, 0, 0);
      Oacc[ct] = __builtin_amdgcn_mfma_f32_16x16x32_bf16(al, sh, Oacc[ct], 0, 0, 0);
    }
  }
  __syncthreads();

#pragma unroll
  for (int t = 0; t < 4; ++t)
#pragma unroll
    for (int i = 0; i < 4; ++i) {
      const int n_loc = w * 16 + kg * 4 + i;
      const int m_loc = t * 16 + fr;
      const float v = (m_loc <= n_loc) ? Wacc[t][i] : 0.f;
      bf16 h, l;
      split2(v, h, l);
      sKWh[n_loc * 64 + m_loc] = h;
      sKWl[n_loc * 64 + m_loc] = l;
    }
  __syncthreads();

  const int kmax = (w < 2) ? 1 : 2;
  for (int ks = 0; ks < kmax; ++ks) {
    const int aoff = (w * 16 + fr) * 64 + ks * 32 + kg * 8;
    const bf16x8 ah = *reinterpret_cast<const bf16x8*>(&sKWh[aoff]);
    const bf16x8 al = *reinterpret_cast<const bf16x8*>(&sKWl[aoff]);
#pragma unroll
    for (int ct = 0; ct < 5; ++ct) {
      const int boff = (ct * 16 + fr) * 64 + ks * 32 + kg * 8;
      const bf16x8 bh_ = *reinterpret_cast<const bf16x8*>(&sVh[boff]);
      const bf16x8 bl_ = *reinterpret_cast<const bf16x8*>(&sVl[boff]);
      Oacc[ct] = __builtin_amdgcn_mfma_f32_16x16x32_bf16(ah, bh_, Oacc[ct], 0, 0, 0);
      Oacc[ct] = __builtin_amdgcn_mfma_f32_16x16x32_bf16(ah, bl_, Oacc[ct], 0, 0, 0);
      Oacc[ct] = __builtin_amdgcn_mfma_f32_16x16x32_bf16(al, bh_, Oacc[ct], 0, 0, 0);
    }
  }

  float inv[4];
#pragma unroll
  for (int i = 0; i < 4; ++i) {
    float r = Oacc[4][i];
    r += __shfl_xor(r, 1);
    r += __shfl_xor(r, 2);
    r += __shfl_xor(r, 4);
    r += __shfl_xor(r, 8);
    inv[i] = 1.f / fmaxf(r, EPS);
  }

  const int b = bh >> 4, hh = bh & 15;
#pragma unroll
  for (int i = 0; i < 4; ++i) {
    const int nglob = c * CHK + w * 16 + kg * 4 + i;
    const size_t rowb = ((size_t)nglob * Bb + b) * E + (size_t)hh * D;
#pragma unroll
    for (int t = 0; t < 4; ++t) {
      const float v = Oacc[t][i] * inv[i];
      bf16 h, l;
      split2(v, h, l);
      Ohi[rowb + t * 16 + fr] = h;
      Olo[rowb + t * 16 + fr] = l;
    }
  }
}

} // namespace

extern "C" void kernel_launch(void* const* d_in, const int* in_sizes, int n_in,
                              void* d_out, int out_size, void* d_ws, size_t ws_size,
                              hipStream_t stream) {
  (void)in_sizes; (void)n_in; (void)out_size; (void)ws_size;
  const float* query = (const float*)d_in[0];
  const float* key_  = (const float*)d_in[1];
  const float* value = (const float*)d_in[2];
  const float* q_w   = (const float*)d_in[3];
  const float* q_b   = (const float*)d_in[4];
  const float* k_w   = (const float*)d_in[5];
  const float* k_b   = (const float*)d_in[6];
  const float* v_w   = (const float*)d_in[7];
  const float* v_b   = (const float*)d_in[8];
  const float* out_w = (const float*)d_in[9];
  const float* out_b = (const float*)d_in[10];
  float* out = (float*)d_out;

  float* ws = (float*)d_ws;
  const size_t SZ = (size_t)M * E;        // 4,194,304 floats per f32 tensor
  float* q_ws = ws;                       // [0, SZ)
  float* k_ws = ws + SZ;                  // [SZ, 2SZ)
  float* v_ws = ws + 2 * SZ;              // [2SZ, 3SZ)
  float* apair = ws + 3 * SZ;             // [3SZ, 4SZ): A hi/lo OR Ohi/Olo
  float* st = ws + 4 * SZ;                // 4.26M floats
  bf16* Ahi = (bf16*)apair;
  bf16* Alo = (bf16*)(apair + SZ / 2);
  bf16* Whi = (bf16*)(st + (size_t)STSZ * BH * NC);
  bf16* Wlo = Whi + (size_t)E * E;
  bf16* Ohi = Ahi;                        // apair dead after gemm v
  bf16* Olo = Alo;

  const int n8A = (int)(SZ / 8);          // 524288
  const int n8W = E * E / 8;              // 131072
  const dim3 gsp((n8A + n8W) / 256);      // 2560
  const dim3 gspW(n8W / 256);             // 512
  const dim3 gg(E / GBN, M / GBM);        // (16, 32) = 512 blocks

  // q projection (relu+rope fused in epilogue)
  hipLaunchKernelGGL(split_conv2, gsp, dim3(256), 0, stream, query, Ahi, Alo, n8A, q_w, Whi, Wlo, n8W);
  hipLaunchKernelGGL((gemm_split<1, true>), gg, dim3(256), 0, stream, Ahi, Alo, Whi, Wlo, q_b, q_ws);
  // k projection (relu+rope fused)
  hipLaunchKernelGGL(split_conv2, gsp, dim3(256), 0, stream, key_, Ahi, Alo, n8A, k_w, Whi, Wlo, n8W);
  hipLaunchKernelGGL((gemm_split<1, true>), gg, dim3(256), 0, stream, Ahi, Alo, Whi, Wlo, k_b, k_ws);
  // v projection
  hipLaunchKernelGGL(split_conv2, gsp, dim3(256), 0, stream, value, Ahi, Alo, n8A, v_w, Whi, Wlo, n8W);
  hipLaunchKernelGGL((gemm_split<1, false>), gg, dim3(256), 0, stream, Ahi, Alo, Whi, Wlo, v_b, v_ws);
  // attention
  hipLaunchKernelGGL(attn_state, dim3(BH * NC), dim3(256), 0, stream, k_ws, v_ws, st);
  hipLaunchKernelGGL(attn_scan, dim3(BH, (STSZ + 255) / 256), dim3(256), 0, stream, st);
  hipLaunchKernelGGL(attn_out, dim3(BH * NC), dim3(256), 0, stream, q_ws, k_ws, v_ws, st, Ohi, Olo);
  // output projection (A already split by attn_out)
  hipLaunchKernelGGL(split_conv2, gspW, dim3(256), 0, stream, out_w, Whi, Wlo, n8W, out_w, Whi, Wlo, 0);
  hipLaunchKernelGGL((gemm_split<0, false>), gg, dim3(256), 0, stream, Ohi, Olo, Whi, Wlo, out_b, out);
}